// Round 1
// baseline (140.794 us; speedup 1.0000x reference)
//
#include <hip/hip_runtime.h>
#include <stdint.h>

typedef float f32x4 __attribute__((ext_vector_type(4)));
typedef __bf16 bf16x8 __attribute__((ext_vector_type(8)));

#define NROWS 65536   // 16 * 4096 x-rows
#define NCODES 4096
#define NDIM 64
#define NSPLIT 4      // m-split: waves per row-group
#define TILES 64      // 1024 codes per stripe / 16 per tile

// ws layout (bytes):
//   [0x000000, 0x080000): codes bf16      4096*64*2 = 512 KB
//   [0x080000, 0x084000): nc2 = -||c||^2  float[4096]
//   [0x100000, 0x200000): tarr float[NROWS*NSPLIT]
//   [0x200000, 0x300000): marr int  [NROWS*NSPLIT]
//   [0x300000, 0x340000): x2   float[NROWS]
// total 3.25 MB of d_ws

__global__ __launch_bounds__(256) void prep_codes_k(const float* __restrict__ codes,
                                                    __bf16* __restrict__ cb,
                                                    float* __restrict__ nc2) {
  int m = blockIdx.x * blockDim.x + threadIdx.x;
  if (m >= NCODES) return;
  const float* src = codes + m * NDIM;
  float s = 0.f;
#pragma unroll
  for (int c = 0; c < 8; c++) {
    f32x4 v0 = *(const f32x4*)(src + c * 8);
    f32x4 v1 = *(const f32x4*)(src + c * 8 + 4);
    bf16x8 o;
#pragma unroll
    for (int j = 0; j < 4; j++) {
      o[j]     = (__bf16)v0[j];
      o[j + 4] = (__bf16)v1[j];
      s += v0[j] * v0[j] + v1[j] * v1[j];
    }
    *(bf16x8*)(cb + m * NDIM + c * 8) = o;
  }
  nc2[m] = -s;
}

// Each wave: 64 rows (4 row-tiles of 16) x one 1024-code stripe.
// A-frag layout (mfma_f32_16x16x32_bf16): lane holds A[m = lane&15][k = quad*8 + j].
// B operand identical pattern on codes[m][d] (codes are B^T row-major).
// C/D layout: col = lane&15, row = quad*4 + reg   (m89/m91-verified).
__global__ __launch_bounds__(256, 4) void nn_main(const float* __restrict__ x,
                                                  const __bf16* __restrict__ cb,
                                                  const float* __restrict__ nc2,
                                                  float* __restrict__ tarr,
                                                  int* __restrict__ marr,
                                                  float* __restrict__ x2arr) {
  const int lane   = threadIdx.x & 63;
  const int wg     = (blockIdx.x * 256 + threadIdx.x) >> 6;  // 0..4095
  const int stripe = wg & (NSPLIT - 1);
  const int rowgrp = wg >> 2;  // 0..1023
  const int col    = lane & 15;
  const int quad   = lane >> 4;

  // ---- Load A fragments once (fp32 -> bf16 in-kernel) + ||x||^2 ----
  bf16x8 a[4][2];
  float x2part[4];
#pragma unroll
  for (int rt = 0; rt < 4; rt++) {
    const int row = rowgrp * 64 + rt * 16 + col;
    const float* xr = x + row * NDIM + quad * 8;
    float p = 0.f;
#pragma unroll
    for (int kc = 0; kc < 2; kc++) {
      f32x4 v0 = *(const f32x4*)(xr + kc * 32);
      f32x4 v1 = *(const f32x4*)(xr + kc * 32 + 4);
      bf16x8 af;
#pragma unroll
      for (int j = 0; j < 4; j++) {
        af[j]     = (__bf16)v0[j];
        af[j + 4] = (__bf16)v1[j];
        p += v0[j] * v0[j] + v1[j] * v1[j];
      }
      a[rt][kc] = af;
    }
    x2part[rt] = p;
  }
  // reduce x2 across the 4 quads (lanes r, r+16, r+32, r+48 hold same row)
#pragma unroll
  for (int rt = 0; rt < 4; rt++) {
    float p = x2part[rt];
    p += __shfl_xor(p, 16);
    p += __shfl_xor(p, 32);
    x2part[rt] = p;
  }
  if (stripe == 0 && quad == 0) {
#pragma unroll
    for (int rt = 0; rt < 4; rt++) x2arr[rowgrp * 64 + rt * 16 + col] = x2part[rt];
  }

  // ---- Main loop over this stripe's 64 code-tiles ----
  float bestT[4][4];
  int bestM[4][4];
#pragma unroll
  for (int rt = 0; rt < 4; rt++)
#pragma unroll
    for (int j = 0; j < 4; j++) {
      bestT[rt][j] = -3.0e38f;
      bestM[rt][j] = 0;
    }

  const int cbase0 = stripe * 1024;
  const __bf16* bptr = cb + (cbase0 + col) * NDIM + quad * 8;
  const float* nptr = nc2 + cbase0 + col;

  bf16x8 b0 = *(const bf16x8*)(bptr);
  bf16x8 b1 = *(const bf16x8*)(bptr + 32);
  float nv = *nptr;

  for (int t = 0; t < TILES; t++) {
    // prefetch next tile's B-frags while this tile computes
    bf16x8 nb0, nb1;
    float nnv;
    if (t < TILES - 1) {
      nb0 = *(const bf16x8*)(bptr + 1024);
      nb1 = *(const bf16x8*)(bptr + 1024 + 32);
      nnv = nptr[16];
    }
    const int mi = cbase0 + t * 16 + col;
#pragma unroll
    for (int rt = 0; rt < 4; rt++) {
      f32x4 acc = __builtin_amdgcn_mfma_f32_16x16x32_bf16(a[rt][0], b0, (f32x4){0.f, 0.f, 0.f, 0.f}, 0, 0, 0);
      acc = __builtin_amdgcn_mfma_f32_16x16x32_bf16(a[rt][1], b1, acc, 0, 0, 0);
#pragma unroll
      for (int j = 0; j < 4; j++) {
        float tv = fmaf(2.0f, acc[j], nv);  // 2*dot - ||c||^2
        if (tv > bestT[rt][j]) {
          bestT[rt][j] = tv;
          bestM[rt][j] = mi;
        }
      }
    }
    b0 = nb0;
    b1 = nb1;
    nv = nnv;
    bptr += 1024;  // 16 code rows * 64 dims
    nptr += 16;
  }

  // ---- butterfly argmax across the 16 lanes sharing each row; write per-stripe slot ----
#pragma unroll
  for (int rt = 0; rt < 4; rt++) {
#pragma unroll
    for (int j = 0; j < 4; j++) {
      float bt = bestT[rt][j];
      int bm = bestM[rt][j];
#pragma unroll
      for (int off = 1; off < 16; off <<= 1) {
        float ot = __shfl_xor(bt, off);
        int om = __shfl_xor(bm, off);
        if (ot > bt || (ot == bt && om < bm)) {
          bt = ot;
          bm = om;
        }
      }
      if (col == 0) {
        const int row = rowgrp * 64 + rt * 16 + quad * 4 + j;
        tarr[row * NSPLIT + stripe] = bt;
        marr[row * NSPLIT + stripe] = bm;
      }
    }
  }
}

__global__ __launch_bounds__(256) void nn_final(const float* __restrict__ tarr,
                                                const int* __restrict__ marr,
                                                const float* __restrict__ x2arr,
                                                int* __restrict__ out) {
  const int row = blockIdx.x * blockDim.x + threadIdx.x;
  if (row >= NROWS) return;
  float bt = tarr[row * NSPLIT];
  int bm = marr[row * NSPLIT];
#pragma unroll
  for (int s = 1; s < NSPLIT; s++) {
    float t = tarr[row * NSPLIT + s];
    int m = marr[row * NSPLIT + s];
    if (t > bt || (t == bt && m < bm)) {
      bt = t;
      bm = m;
    }
  }
  const float d2 = x2arr[row] - bt;  // min squared distance
  out[row] = (d2 <= 0.1f) ? bm : -1;
}

extern "C" void kernel_launch(void* const* d_in, const int* in_sizes, int n_in,
                              void* d_out, int out_size, void* d_ws, size_t ws_size,
                              hipStream_t stream) {
  const float* x = (const float*)d_in[0];      // [65536][64] fp32
  const float* codes = (const float*)d_in[1];  // [4096][64] fp32
  int* out = (int*)d_out;                      // [65536] int32

  char* ws = (char*)d_ws;
  __bf16* cb = (__bf16*)ws;                     // 512 KB
  float* nc2 = (float*)(ws + 0x080000);         // 16 KB
  float* tarr = (float*)(ws + 0x100000);        // 1 MB
  int* marr = (int*)(ws + 0x200000);            // 1 MB
  float* x2arr = (float*)(ws + 0x300000);       // 256 KB

  prep_codes_k<<<16, 256, 0, stream>>>(codes, cb, nc2);
  nn_main<<<1024, 256, 0, stream>>>(x, cb, nc2, tarr, marr, x2arr);
  nn_final<<<256, 256, 0, stream>>>(tarr, marr, x2arr, out);
}